// Round 1
// 528.396 us; speedup vs baseline: 1.1449x; 1.1449x over previous
//
#include <hip/hip_runtime.h>

#define BATCH 16
#define CIN 512
#define COUT 512
#define RES 64
#define K_TILES 72   // 9 taps * 512 cin / BK=64

typedef __attribute__((ext_vector_type(8))) short bf16x8;
typedef __attribute__((ext_vector_type(4))) float f32x4;

// zero-initialized device global: boundary-tap source for global_load_lds.
__device__ __align__(16) unsigned short g_zero[64];

static __device__ __forceinline__ unsigned short f2bf(float f) {
    unsigned int u = __float_as_uint(f);
    u += 0x7fffu + ((u >> 16) & 1u);   // round-to-nearest-even
    return (unsigned short)(u >> 16);
}

static __device__ __forceinline__ void gload16(const void* g, void* l) {
    __builtin_amdgcn_global_load_lds(
        (const __attribute__((address_space(1))) void*)g,
        (__attribute__((address_space(3))) void*)l, 16, 0, 0);
}

// ---- fused prep1: blocks [0,2048): styles[b][i] ; blocks [2048,2560): wA + wsq ----
__global__ void k_prep1(const float* __restrict__ w, const float* __restrict__ aw,
                        const float* __restrict__ ab, const float* __restrict__ weight,
                        float* __restrict__ styles, unsigned short* __restrict__ wA,
                        float* __restrict__ wsq) {
    if (blockIdx.x < 2048) {
        int wid  = (blockIdx.x * blockDim.x + threadIdx.x) >> 6;
        int lane = threadIdx.x & 63;
        int b = wid >> 9, i = wid & 511;
        const float* wrow = w + b * 512;
        const float* arow = aw + (size_t)i * 512;
        float acc = 0.f;
        for (int k = lane; k < 512; k += 64) acc += wrow[k] * arow[k];
        for (int off = 32; off; off >>= 1) acc += __shfl_down(acc, off, 64);
        if (lane == 0) styles[wid] = acc * 0.04419417382415922f + ab[i];
    } else {
        int o = blockIdx.x - 2048;
        __shared__ float lw[4608];
        for (int idx = threadIdx.x; idx < 4608; idx += 256)
            lw[idx] = weight[(size_t)o * 4608 + idx];
        __syncthreads();
        int i = threadIdx.x * 2;
        float sq0 = 0.f, sq1 = 0.f;
#pragma unroll
        for (int t = 0; t < 9; ++t) {
            float v0 = lw[i * 9 + t], v1 = lw[(i + 1) * 9 + t];
            sq0 += v0 * v0; sq1 += v1 * v1;
            unsigned* dst = (unsigned*)(wA + (((size_t)t * COUT + o) << 9));
            dst[threadIdx.x] = (unsigned)f2bf(v0) | ((unsigned)f2bf(v1) << 16);
        }
        *(float2*)(wsq + ((size_t)o << 9) + i) = make_float2(sq0, sq1);
    }
}

// ---- dcoefs[b][o] = rsqrt(sum_i styles^2 * wsq[o,i] + 1e-8) ----
__global__ void k_dcoefs(const float* __restrict__ wsq, const float* __restrict__ styles,
                         float* __restrict__ dcoefs) {
    int wid  = (blockIdx.x * blockDim.x + threadIdx.x) >> 6;
    int lane = threadIdx.x & 63;
    int b = wid >> 9, o = wid & 511;
    const float* srow = styles + b * 512;
    const float* qrow = wsq + ((size_t)o << 9);
    float acc = 0.f;
    for (int i = lane; i < 512; i += 64) {
        float s = srow[i];
        acc += s * s * qrow[i];
    }
    for (int off = 32; off; off >>= 1) acc += __shfl_down(acc, off, 64);
    if (lane == 0) dcoefs[wid] = rsqrtf(acc + 1e-8f);
}

// ---- xt[b][h][w][i] = bf16(x[b][i][h][w] * styles[b][i])  (CHW->HWC + style fold) ----
__global__ void k_xpose(const float* __restrict__ x, const float* __restrict__ styles,
                        unsigned short* __restrict__ xt) {
    int bh = blockIdx.x;          // b*64 + h
    int ic = blockIdx.y;          // channel chunk of 32
    int b = bh >> 6, h = bh & 63;
    __shared__ float tile[32][65];
    __shared__ float st[32];
    const float* src = x + ((size_t)b * 512 + ic * 32) * 4096 + h * 64;
    if (threadIdx.x < 32) st[threadIdx.x] = styles[b * 512 + ic * 32 + threadIdx.x];
    for (int idx = threadIdx.x; idx < 512; idx += 256) {
        int c = idx >> 4, w4 = (idx & 15) * 4;
        float4 v = *(const float4*)(src + (size_t)c * 4096 + w4);
        tile[c][w4] = v.x; tile[c][w4 + 1] = v.y; tile[c][w4 + 2] = v.z; tile[c][w4 + 3] = v.w;
    }
    __syncthreads();
    int w = threadIdx.x >> 2, cg = (threadIdx.x & 3) * 8;
    bf16x8 v;
#pragma unroll
    for (int j = 0; j < 8; ++j) v[j] = (short)f2bf(tile[cg + j][w] * st[cg + j]);
    *(bf16x8*)(xt + (((size_t)bh * 64 + w) << 9) + ic * 32 + cg) = v;
}

// ---------------- main conv: implicit GEMM, 256x256 tile, 8-phase schedule ----
// 8 waves (2M x 4N), BK=64, LDS 128 KiB double-buffered, counted vmcnt (T3+T4),
// XOR-swizzled LDS (T2: phys_quad = log_quad ^ (slot_row & 7), 16B quads in 128B rows),
// setprio around each MFMA cluster (T5).
//
// LDS slot geometry (per matrix, per dbuf): slot q holds 128 rows x 64 halfs.
//   A slot q: tile rows  blk*128 + q*64 + r   (blk = wm of the reader)
//   B slot q: tile pixels (j>>5)*64 + q*32 + (j&31)  for slot row j
// Stage: linear LDS dest (wave-uniform base + lane*16), inverse-swizzled GLOBAL src.
__global__ __launch_bounds__(512, 2)
void k_conv(const unsigned short* __restrict__ wA, const unsigned short* __restrict__ xt,
            const float* __restrict__ dcoefs,
            const float* __restrict__ noise, const float* __restrict__ nstr,
            const float* __restrict__ bias, float* __restrict__ out) {
    __shared__ __align__(16) unsigned short lA[2][2][8192];   // [dbuf][slot][128*64]
    __shared__ __align__(16) unsigned short lB[2][2][8192];

    const int tid  = threadIdx.x;
    const int lane = tid & 63;
    const int wave = tid >> 6;
    const int wm = wave >> 2;      // 0..1  (M waves)
    const int wn = wave & 3;       // 0..3  (N waves)

    // XCD-aware bijective swizzle (nwg=512, 512%8==0): o-block fastest so the two
    // blocks sharing a B-tile are consecutive within an XCD.
    const int orig  = blockIdx.x;
    const int wgid  = (orig & 7) * 64 + (orig >> 3);
    const int o_blk = wgid & 1;
    const int ptile = wgid >> 1;           // 0..255
    const int b     = ptile >> 4;          // batch
    const int h0    = (ptile & 15) << 2;   // 4 image rows per 256-pixel tile
    const int o0    = o_blk * 256;

    // staging constants: slot row j = s*64 + jrow; swizzled source quad
    const int jrow  = tid >> 3;                                // 0..63
    const int qsrc8 = (((tid & 7) ^ (jrow & 7)) & 7) * 8;      // halfs

    // fragment-read constants
    const int a_row_byte = (wm * 64 + (lane & 15)) * 128;
    const int b_row_byte = (wn * 32 + (lane & 15)) * 128;
    const int q0_byte = ((((lane >> 4)) ^ (lane & 7)) & 7) * 16;       // ks=0
    const int q1_byte = ((((lane >> 4) | 4) ^ (lane & 7)) & 7) * 16;   // ks=1

    auto stage_a = [&](int d, int q, int ktt) {
        const int t = ktt >> 3, i0 = (ktt & 7) << 6;
        const unsigned short* g0 =
            wA + (((size_t)(t * COUT + o0 + q * 64 + jrow)) << 9) + i0 + qsrc8;
        char* lb = (char*)&lA[d][q][0] + wave * 1024;
        gload16(g0, lb);                       // s=0: tile rows q*64 + [0,64)
        gload16(g0 + (128 << 9), lb + 8192);   // s=1: tile rows 128 + q*64 + [0,64)
    };
    auto stage_b = [&](int d, int q, int ktt) {
        const int t = ktt >> 3, i0 = (ktt & 7) << 6;
        const int dy = t / 3 - 1, dx = t - (t / 3) * 3 - 1;
        const int ww = q * 32 + (jrow & 31) + dx;
        const int hh = h0 + (jrow >> 5) + dy;            // s=0 row; s=1 is +2
        const bool wok = (unsigned)ww < 64u;
        const unsigned short* gz = g_zero + qsrc8;
        const unsigned short* p0 = (wok && (unsigned)hh < 64u)
            ? xt + (((size_t)(b * 4096 + hh * 64 + ww)) << 9) + i0 + qsrc8 : gz;
        const unsigned short* p1 = (wok && (unsigned)(hh + 2) < 64u)
            ? xt + (((size_t)(b * 4096 + (hh + 2) * 64 + ww)) << 9) + i0 + qsrc8 : gz;
        char* lb = (char*)&lB[d][q][0] + wave * 1024;
        gload16(p0, lb);
        gload16(p1, lb + 8192);
    };

    f32x4 acc[8][4];
#pragma unroll
    for (int i = 0; i < 8; ++i)
#pragma unroll
        for (int j = 0; j < 4; ++j) acc[i][j] = (f32x4){0.f, 0.f, 0.f, 0.f};

    // ---- prologue: kt0 fully, kt1 A0/B0/A1; counted waits (loads, not halves) ----
    stage_a(0, 0, 0); stage_b(0, 0, 0); stage_a(0, 1, 0); stage_b(0, 1, 0);
    asm volatile("s_waitcnt vmcnt(4)" ::: "memory");
    stage_a(1, 0, 1); stage_b(1, 0, 1); stage_a(1, 1, 1);
    asm volatile("s_waitcnt vmcnt(6)" ::: "memory");   // kt0 fully landed
    __builtin_amdgcn_s_barrier();

    bf16x8 a_lo[4][2], a_hi[4][2], b_lo[2][2], b_hi[2][2];

    for (int kt = 0; kt < K_TILES; ++kt) {
        const int cur = kt & 1;
        const char* baseA = (const char*)&lA[cur][0][0];
        const char* baseB = (const char*)&lB[cur][0][0];

        // ---- phase 0: read A-lo + B-lo (12 ds_reads), stage (kt+1).B1, Q00 ----
#pragma unroll
        for (int f = 0; f < 4; ++f) {
            a_lo[f][0] = *(const bf16x8*)(baseA + a_row_byte + f * 2048 + q0_byte);
            a_lo[f][1] = *(const bf16x8*)(baseA + a_row_byte + f * 2048 + q1_byte);
        }
#pragma unroll
        for (int g = 0; g < 2; ++g) {
            b_lo[g][0] = *(const bf16x8*)(baseB + b_row_byte + g * 2048 + q0_byte);
            b_lo[g][1] = *(const bf16x8*)(baseB + b_row_byte + g * 2048 + q1_byte);
        }
        if (kt + 1 < K_TILES) stage_b(cur ^ 1, 1, kt + 1);
        __builtin_amdgcn_s_barrier();
        asm volatile("s_waitcnt lgkmcnt(0)" ::: "memory");
        __builtin_amdgcn_sched_barrier(0);
        __builtin_amdgcn_s_setprio(1);
#pragma unroll
        for (int f = 0; f < 4; ++f)
#pragma unroll
            for (int g = 0; g < 2; ++g) {
                f32x4 c = acc[f][g];
                c = __builtin_amdgcn_mfma_f32_16x16x32_bf16(a_lo[f][0], b_lo[g][0], c, 0, 0, 0);
                c = __builtin_amdgcn_mfma_f32_16x16x32_bf16(a_lo[f][1], b_lo[g][1], c, 0, 0, 0);
                acc[f][g] = c;
            }
        __builtin_amdgcn_s_setprio(0);
        __builtin_amdgcn_s_barrier();

        // ---- phase 1: read B-hi, stage (kt+2).A0 (A0 slot free after ph0), Q01 ----
#pragma unroll
        for (int g = 0; g < 2; ++g) {
            b_hi[g][0] = *(const bf16x8*)(baseB + 16384 + b_row_byte + g * 2048 + q0_byte);
            b_hi[g][1] = *(const bf16x8*)(baseB + 16384 + b_row_byte + g * 2048 + q1_byte);
        }
        if (kt + 2 < K_TILES) stage_a(cur, 0, kt + 2);
        __builtin_amdgcn_s_barrier();
        asm volatile("s_waitcnt lgkmcnt(0)" ::: "memory");
        __builtin_amdgcn_sched_barrier(0);
        __builtin_amdgcn_s_setprio(1);
#pragma unroll
        for (int f = 0; f < 4; ++f)
#pragma unroll
            for (int g = 0; g < 2; ++g) {
                f32x4 c = acc[f][2 + g];
                c = __builtin_amdgcn_mfma_f32_16x16x32_bf16(a_lo[f][0], b_hi[g][0], c, 0, 0, 0);
                c = __builtin_amdgcn_mfma_f32_16x16x32_bf16(a_lo[f][1], b_hi[g][1], c, 0, 0, 0);
                acc[f][2 + g] = c;
            }
        __builtin_amdgcn_s_setprio(0);
        __builtin_amdgcn_s_barrier();

        // ---- phase 2: read A-hi, stage (kt+2).B0 (B0 slot free after ph0), Q11 ----
#pragma unroll
        for (int f = 0; f < 4; ++f) {
            a_hi[f][0] = *(const bf16x8*)(baseA + 16384 + a_row_byte + f * 2048 + q0_byte);
            a_hi[f][1] = *(const bf16x8*)(baseA + 16384 + a_row_byte + f * 2048 + q1_byte);
        }
        if (kt + 2 < K_TILES) stage_b(cur, 0, kt + 2);
        __builtin_amdgcn_s_barrier();
        asm volatile("s_waitcnt lgkmcnt(0)" ::: "memory");
        __builtin_amdgcn_sched_barrier(0);
        __builtin_amdgcn_s_setprio(1);
#pragma unroll
        for (int f = 0; f < 4; ++f)
#pragma unroll
            for (int g = 0; g < 2; ++g) {
                f32x4 c = acc[4 + f][2 + g];
                c = __builtin_amdgcn_mfma_f32_16x16x32_bf16(a_hi[f][0], b_hi[g][0], c, 0, 0, 0);
                c = __builtin_amdgcn_mfma_f32_16x16x32_bf16(a_hi[f][1], b_hi[g][1], c, 0, 0, 0);
                acc[4 + f][2 + g] = c;
            }
        __builtin_amdgcn_s_setprio(0);
        __builtin_amdgcn_s_barrier();

        // ---- phase 3: stage (kt+2).A1 (A1 slot free after ph2), counted vmcnt, Q10 ----
        if (kt + 2 < K_TILES) {
            stage_a(cur, 1, kt + 2);
            // leave (kt+2).A0/B0/A1 = 6 loads in flight; everything через (kt+1).B1 landed
            asm volatile("s_waitcnt vmcnt(6)" ::: "memory");
        } else if (kt + 1 < K_TILES) {
            asm volatile("s_waitcnt vmcnt(0)" ::: "memory");   // tail: drain for last tile
        }
        __builtin_amdgcn_s_barrier();
        __builtin_amdgcn_s_setprio(1);
#pragma unroll
        for (int f = 0; f < 4; ++f)
#pragma unroll
            for (int g = 0; g < 2; ++g) {
                f32x4 c = acc[4 + f][g];
                c = __builtin_amdgcn_mfma_f32_16x16x32_bf16(a_hi[f][0], b_lo[g][0], c, 0, 0, 0);
                c = __builtin_amdgcn_mfma_f32_16x16x32_bf16(a_hi[f][1], b_lo[g][1], c, 0, 0, 0);
                acc[4 + f][g] = c;
            }
        __builtin_amdgcn_s_setprio(0);
        __builtin_amdgcn_s_barrier();
    }

    // ---- epilogue ----
    const float ns = nstr[0];
    const float* dcb = dcoefs + b * 512;
    const int pbase = (ptile & 15) * 256 + wn * 64 + (lane & 15);
#pragma unroll
    for (int fm = 0; fm < 8; ++fm) {
        const int ob = o0 + wm * 128 + fm * 16 + ((lane >> 4) << 2);
#pragma unroll
        for (int fn = 0; fn < 4; ++fn) {
            const int p = pbase + fn * 16;
            const float nval = noise[p] * ns;
#pragma unroll
            for (int rg = 0; rg < 4; ++rg) {
                const int o = ob + rg;
                float v = acc[fm][fn][rg] * dcb[o] + nval + bias[o];
                v = (v > 0.f ? v : 0.2f * v) * 1.41421356f;
                out[((size_t)(b * COUT + o) << 12) + p] = v;
            }
        }
    }
}

// -------- fallback: fully self-contained fp32 conv (touches NO workspace) --------
__global__ void k_conv_naive(const float* __restrict__ x, const float* __restrict__ w,
                             const float* __restrict__ weight,
                             const float* __restrict__ aw, const float* __restrict__ ab,
                             const float* __restrict__ noise, const float* __restrict__ nstr,
                             const float* __restrict__ bias, float* __restrict__ out) {
    const int o = blockIdx.x, b = blockIdx.y;
    __shared__ float ss[512];
    __shared__ float red[256];
    const float* wv = w + b * 512;
    for (int i = threadIdx.x; i < 512; i += 256) {
        const float* arow = aw + (size_t)i * 512;
        float acc = 0.f;
        for (int k = 0; k < 512; ++k) acc += wv[k] * arow[k];
        ss[i] = acc * 0.04419417382415922f + ab[i];
    }
    __syncthreads();
    float part = 0.f;
    for (int i = threadIdx.x; i < 512; i += 256) {
        float s = ss[i], sq = 0.f;
#pragma unroll
        for (int k = 0; k < 9; ++k) { float v = weight[((size_t)o * 512 + i) * 9 + k]; sq += v * v; }
        part += s * s * sq;
    }
    red[threadIdx.x] = part;
    __syncthreads();
    for (int st = 128; st; st >>= 1) {
        if (threadIdx.x < st) red[threadIdx.x] += red[threadIdx.x + st];
        __syncthreads();
    }
    const float dcoef = rsqrtf(red[0] + 1e-8f);

    float acc[16];
#pragma unroll
    for (int j = 0; j < 16; ++j) acc[j] = 0.f;
    for (int i = 0; i < 512; ++i) {
        const float s = ss[i];
        float wk[9];
#pragma unroll
        for (int k = 0; k < 9; ++k) wk[k] = weight[((size_t)o * 512 + i) * 9 + k] * s;
        const float* xp = x + ((size_t)b * 512 + i) * 4096;
#pragma unroll
        for (int j = 0; j < 16; ++j) {
            const int p = (j << 8) + threadIdx.x;
            const int h = p >> 6, ww = p & 63;
            float a = acc[j];
#pragma unroll
            for (int ky = 0; ky < 3; ++ky) {
                int hh = h + ky - 1;
                if ((unsigned)hh < 64u) {
#pragma unroll
                    for (int kx = 0; kx < 3; ++kx) {
                        int wv2 = ww + kx - 1;
                        if ((unsigned)wv2 < 64u) a += wk[ky * 3 + kx] * xp[hh * 64 + wv2];
                    }
                }
            }
            acc[j] = a;
        }
    }
    const float ns = nstr[0], bs = bias[o];
#pragma unroll
    for (int j = 0; j < 16; ++j) {
        int p = (j << 8) + threadIdx.x;
        float v = acc[j] * dcoef + noise[p] * ns + bs;
        v = (v > 0.f ? v : 0.2f * v) * 1.41421356f;
        out[((size_t)(b * COUT + o) << 12) + p] = v;
    }
}

extern "C" void kernel_launch(void* const* d_in, const int* in_sizes, int n_in,
                              void* d_out, int out_size, void* d_ws, size_t ws_size,
                              hipStream_t stream) {
    const float* x   = (const float*)d_in[0];
    const float* w   = (const float*)d_in[1];
    const float* wt  = (const float*)d_in[2];
    const float* aw  = (const float*)d_in[3];
    const float* ab  = (const float*)d_in[4];
    const float* bs  = (const float*)d_in[5];
    const float* nc  = (const float*)d_in[6];
    const float* nst = (const float*)d_in[7];
    float* out = (float*)d_out;

    char* ws = (char*)d_ws;
    float* styles = (float*)ws;                                  // 32 KB
    float* dcoefs = (float*)(ws + 32 * 1024);                    // 32 KB
    float* wsq    = (float*)(ws + 64 * 1024);                    // 1 MB
    unsigned short* wA = (unsigned short*)(ws + (2 << 20));      // 4.7 MB
    unsigned short* xt = (unsigned short*)(ws + (2 << 20) + 4718592ull); // 67.1 MB
    const size_t need = (size_t)(2 << 20) + 4718592ull + 67108864ull;    // ~70.5 MB

    if (d_ws != nullptr && ws_size >= need) {
        k_prep1<<<2560, 256, 0, stream>>>(w, aw, ab, wt, styles, wA, wsq);
        k_dcoefs<<<2048, 256, 0, stream>>>(wsq, styles, dcoefs);
        k_xpose<<<dim3(1024, 16), 256, 0, stream>>>(x, styles, xt);
        k_conv<<<512, 512, 0, stream>>>(wA, xt, dcoefs, nc, nst, bs, out);
    } else {
        k_conv_naive<<<dim3(512, 16), 256, 0, stream>>>(x, w, wt, aw, ab, nc, nst, bs, out);
    }
}